// Round 6
// baseline (181.890 us; speedup 1.0000x reference)
//
#include <hip/hip_runtime.h>

// GPConv1d: out[b,o,kb,w] = sum_{i,j,c,v} G[i,j,kb] W[v,c,o,i] xpad[b,c,j,w+v] + bias[o,kb]
// GEMM view: out[ok][b,w] = sum_kd kern[ok][kd] X[kd][b,w], M=512, N=32768, K=2560
// R6: A-prefetch distance 1 -> 2 (aX/aY/aZ register rotation). Phase compute
//     (~155 cyc MFMA) < L2 latency (~200-400), so distance-1 left a residual
//     stall at every phase-head WAITV (MfmaUtil 50% vs 56% floor share).
//     Distance-2 gives >=310cyc+staging of tolerance. Exact vmcnt ledger:
//     v0/v1: 8, v2: 16 (dA before A_{p+2}), v3: early 4 + 24, v4: early 4 + 8;
//     last cjb 8/8/8/4/0. 15-phase rotation period = 3 cjbs -> loop 2x3 + tail.
//     Everything else from R5 kept: 4x1 wave grid, inline-asm loads w/ manual
//     vmcnt (never 0 until last phase), bf16-prepadded x, Bs XOR swizzle,
//     1 barrier/cjb (lgkm only), T5 setprio.

#define C_    64
#define L_    4096
#define PAD_  2
#define OKch  512
#define XSTR  4104      // padded bf16 x row stride (elems); halo [0,1],[4098,4099]

#define BM    128
#define BN    128
#define BKCJ  64
#define NCJB  8
#define NV    5
#define TILE  8192      // kern tile: 128 rows x 64 cols (16 KB), frag-coalesced
#define WIN   132       // Bs rows: w0-2 .. w0+129
#define BSZ   (WIN * 64)  // one Bs buffer: 8448 elems = 16896 B

typedef __bf16 bf16x8 __attribute__((ext_vector_type(8)));
typedef float floatx4 __attribute__((ext_vector_type(4)));

__device__ __forceinline__ unsigned short f2bf(float f) {
    unsigned int u = __float_as_uint(f);
    u += 0x7FFFu + ((u >> 16) & 1u);
    return (unsigned short)(u >> 16);
}

#define WAIT_LGKM_0() asm volatile("s_waitcnt lgkmcnt(0)" ::: "memory")
#define WAITV_(N) asm volatile("s_waitcnt vmcnt(" #N ")" ::: "memory")
#define WAITV(N) do { WAITV_(N); __builtin_amdgcn_sched_barrier(0); } while (0)

__device__ __forceinline__ void barrier_raw() {
    asm volatile("" ::: "memory");
    __builtin_amdgcn_sched_barrier(0);
    __builtin_amdgcn_s_barrier();
    __builtin_amdgcn_sched_barrier(0);
    asm volatile("" ::: "memory");
}

// manual global loads (invisible to compiler's waitcnt inserter)
#define GLD_U32(dst, ptr) \
    asm volatile("global_load_dword %0, %1, off" : "=&v"(dst) : "v"(ptr))
#define GLD_A4(a0, a1, a2, a3, ptr)                          \
    asm volatile("global_load_dwordx4 %0, %4, off\n\t"       \
                 "global_load_dwordx4 %1, %4, off offset:1024\n\t" \
                 "global_load_dwordx4 %2, %4, off offset:2048\n\t" \
                 "global_load_dwordx4 %3, %4, off offset:3072"     \
                 : "=&v"(a0), "=&v"(a1), "=&v"(a2), "=&v"(a3) : "v"(ptr))

// ---- kernel 1: prep = build_kern (blocks 0..639) + x->bf16 pad (blocks 640..4735)
__global__ __launch_bounds__(256) void prep(
    const float* __restrict__ W, const float* __restrict__ G,
    const float* __restrict__ x,
    unsigned short* __restrict__ kernT, unsigned short* __restrict__ xp)
{
    const int bid = blockIdx.x;
    const int tid = threadIdx.x;
    if (bid < 640) {
        __shared__ float Gs[512];
        Gs[tid] = G[tid];
        Gs[tid + 256] = G[tid + 256];
        __syncthreads();

        const int idx  = bid * 256 + tid;    // 0..163839
        const int lrow = idx & 15;
        const int quad = (idx >> 4) & 3;
        const int f    = (idx >> 6) & 15;
        const int mq   = f >> 1;
        const int kk2  = f & 1;
        const int t    = idx >> 10;          // (y*8+cjb)*5+v, 0..159
        const int v    = t % 5;
        const int tc   = t / 5;
        const int cjb  = tc & 7;
        const int y    = tc >> 3;
        const int m    = (mq << 4) | lrow;
        const int ok   = (y << 7) | m;
        const int o    = ok >> 3;
        const int kb   = ok & 7;
        const int c    = (cjb << 3) | (kk2 << 2) | quad;

        const float* Wp = W + (((v * C_ + c) * 64 + o) << 3);
        const float4 w0 = *(const float4*)Wp;
        const float4 w1 = *(const float4*)(Wp + 4);
        const float w[8] = {w0.x, w0.y, w0.z, w0.w, w1.x, w1.y, w1.z, w1.w};

        unsigned int pk[4];
        #pragma unroll
        for (int j = 0; j < 8; j++) {
            float s = 0.f;
            #pragma unroll
            for (int i = 0; i < 8; i++)
                s += Gs[i * 64 + j * 8 + kb] * w[i];
            const unsigned short h = f2bf(s);
            if (j & 1) pk[j >> 1] |= (unsigned int)h << 16;
            else       pk[j >> 1]  = h;
        }
        uint4 uu; uu.x = pk[0]; uu.y = pk[1]; uu.z = pk[2]; uu.w = pk[3];
        *reinterpret_cast<uint4*>(
            &kernT[((size_t)t << 13) + (f << 9) + (quad << 7) + (lrow << 3)]) = uu;
    } else {
        const int row = bid - 640;           // 0..4095 = b*512 + cj
        const float* src = x + (size_t)row * L_;
        unsigned short* dst = xp + (size_t)row * XSTR;
        #pragma unroll
        for (int i = 0; i < 4; i++) {
            const int p = (i * 256 + tid) << 2;
            const float4 fv = *reinterpret_cast<const float4*>(src + p);
            const unsigned int u0 = (unsigned int)f2bf(fv.x) | ((unsigned int)f2bf(fv.y) << 16);
            const unsigned int u1 = (unsigned int)f2bf(fv.z) | ((unsigned int)f2bf(fv.w) << 16);
            *reinterpret_cast<unsigned int*>(dst + 2 + p) = u0;
            *reinterpret_cast<unsigned int*>(dst + 4 + p) = u1;
        }
        if (tid == 0) {
            *reinterpret_cast<unsigned int*>(dst) = 0u;          // w' 0,1
            *reinterpret_cast<unsigned int*>(dst + 4098) = 0u;   // w' 4098,4099
        }
    }
}

// ---- staging helpers: item = (kgrp=idx/66, wpair=idx%66) covers rows nn,nn+1
__device__ __forceinline__ void bi_round(const unsigned short* xp, int cj0,
                                         int w0, int round, unsigned int (&d)[8]) {
    const int idx  = round * 256 + (int)threadIdx.x;
    const int kgrp = idx / 66;
    const int wp   = idx - kgrp * 66;
    const unsigned short* p =
        xp + (size_t)(cj0 + (kgrp << 3)) * XSTR + (size_t)(w0 + (wp << 1));
    GLD_U32(d[0], p);
    GLD_U32(d[1], p + XSTR);
    GLD_U32(d[2], p + 2 * XSTR);
    GLD_U32(d[3], p + 3 * XSTR);
    GLD_U32(d[4], p + 4 * XSTR);
    GLD_U32(d[5], p + 5 * XSTR);
    GLD_U32(d[6], p + 6 * XSTR);
    GLD_U32(d[7], p + 7 * XSTR);
}

__device__ __forceinline__ void bi_tail(const unsigned short* xp, int cj0,
                                        int w0, unsigned int (&d)[8]) {
    const int lane = (int)threadIdx.x & 63;
    const int wave = (int)threadIdx.x >> 6;
    if ((lane & 15) == 0) {
        const int idx  = 512 + (wave << 2) + (lane >> 4);
        const int kgrp = idx / 66;
        const int wp   = idx - kgrp * 66;
        const unsigned short* p =
            xp + (size_t)(cj0 + (kgrp << 3)) * XSTR + (size_t)(w0 + (wp << 1));
        GLD_U32(d[0], p);
        GLD_U32(d[1], p + XSTR);
        GLD_U32(d[2], p + 2 * XSTR);
        GLD_U32(d[3], p + 3 * XSTR);
        GLD_U32(d[4], p + 4 * XSTR);
        GLD_U32(d[5], p + 5 * XSTR);
        GLD_U32(d[6], p + 6 * XSTR);
        GLD_U32(d[7], p + 7 * XSTR);
    }
}

__device__ __forceinline__ void st_item(unsigned short* Bw, int kgrp, int nn,
                                        const unsigned int (&d)[8]) {
    const unsigned int lo0 = (d[0] & 0xffffu) | (d[1] << 16);
    const unsigned int hi0 = (d[0] >> 16)     | (d[1] & 0xffff0000u);
    const unsigned int lo1 = (d[2] & 0xffffu) | (d[3] << 16);
    const unsigned int hi1 = (d[2] >> 16)     | (d[3] & 0xffff0000u);
    const unsigned int lo2 = (d[4] & 0xffffu) | (d[5] << 16);
    const unsigned int hi2 = (d[4] >> 16)     | (d[5] & 0xffff0000u);
    const unsigned int lo3 = (d[6] & 0xffffu) | (d[7] << 16);
    const unsigned int hi3 = (d[6] >> 16)     | (d[7] & 0xffff0000u);
    const int s = kgrp ^ (nn & 7);
    uint4 Lv; Lv.x = lo0; Lv.y = lo1; Lv.z = lo2; Lv.w = lo3;
    uint4 Hv; Hv.x = hi0; Hv.y = hi1; Hv.z = hi2; Hv.w = hi3;
    *reinterpret_cast<uint4*>(&Bw[(nn << 6) + (s << 3)]) = Lv;
    *reinterpret_cast<uint4*>(&Bw[((nn + 1) << 6) + ((s ^ 1) << 3)]) = Hv;
}

__device__ __forceinline__ void st_round(unsigned short* Bw, int round,
                                         const unsigned int (&d)[8]) {
    const int idx  = round * 256 + (int)threadIdx.x;
    const int kgrp = idx / 66;
    const int wp   = idx - kgrp * 66;
    st_item(Bw, kgrp, wp << 1, d);
}

__device__ __forceinline__ void st_tail(unsigned short* Bw,
                                        const unsigned int (&d)[8]) {
    const int lane = (int)threadIdx.x & 63;
    const int wave = (int)threadIdx.x >> 6;
    if ((lane & 15) == 0) {
        const int idx  = 512 + (wave << 2) + (lane >> 4);
        const int kgrp = idx / 66;
        const int wp   = idx - kgrp * 66;
        st_item(Bw, kgrp, wp << 1, d);
    }
}

// ---- B-frag reads for one kk2 group: 8 x ds_read_b128, conflict-free (swizzle)
__device__ __forceinline__ void bfread(const unsigned short* BsR, int v, int kk2,
                                       int lrow, int quad, bf16x8 (&f)[8]) {
    const int s7  = (lrow + v) & 7;
    const int col = ((((kk2) << 2) | quad) ^ s7) << 3;
    const int rb  = (lrow + v) << 6;
    #pragma unroll
    for (int nt = 0; nt < 8; nt++)
        f[nt] = *reinterpret_cast<const bf16x8*>(&BsR[rb + (nt << 10) + col]);
}

__device__ __forceinline__ void cl(const bf16x8 (&a)[4], int kk2,
                                   const bf16x8 (&f)[8], floatx4 (&acc)[2][8]) {
    __builtin_amdgcn_s_setprio(1);
    #pragma unroll
    for (int mt = 0; mt < 2; mt++)
        #pragma unroll
        for (int nt = 0; nt < 8; nt++)
            acc[mt][nt] = __builtin_amdgcn_mfma_f32_16x16x32_bf16(
                a[mt * 2 + kk2], f[nt], acc[mt][nt], 0, 0, 0);
    __builtin_amdgcn_s_setprio(0);
}

// ---- kernel 2: MFMA GEMM, 128x128 C-tile, 4x1 wave grid, distance-2 A prefetch
__global__ __launch_bounds__(256, 2) void gpconv_mfma(
    const unsigned short* __restrict__ xp, const unsigned short* __restrict__ kernT,
    const float* __restrict__ bias, float* __restrict__ out)
{
    __shared__ unsigned short Bs[2 * BSZ];  // 33792 B, double-buffered x window

    const int tid  = threadIdx.x;
    const int lane = tid & 63;
    const int wave = tid >> 6;
    const int lrow = lane & 15;
    const int quad = lane >> 4;

    // XCD-aware remap: 4 y-blocks sharing an x-window land on the same XCD
    const int bid = blockIdx.x;              // 0..1023
    const int y   = (bid >> 3) & 3;
    const int xw  = ((bid >> 5) << 3) + (bid & 7);  // 0..255
    const int b   = xw >> 5;
    const int w0  = (xw & 31) * BN;
    const int mBase = y * BM;
    const unsigned short* xb = xp + (size_t)b * (size_t)(512 * XSTR);
    const unsigned short* ky = kernT + (size_t)(y * NCJB) * NV * TILE;
    const unsigned short* abase = ky + (wave << 11) + (lane << 3);  // wave's f0 slot

    floatx4 acc[2][8];
    {
        const floatx4 z = {0.f, 0.f, 0.f, 0.f};
        #pragma unroll
        for (int i2 = 0; i2 < 2; i2++)
            #pragma unroll
            for (int j2 = 0; j2 < 8; j2++) acc[i2][j2] = z;
    }

    bf16x8 bX[4], bY[4], bZ[4];
    unsigned int dA[8], dB[8], dT[8];

    // ---- prologue: window(cjb=0); A0 -> bX, A1 -> bY.
    bi_round(xb, 0, w0, 0, dA);
    bi_round(xb, 0, w0, 1, dB);
    bi_tail(xb, 0, w0, dT);
    GLD_A4(bX[0], bX[1], bX[2], bX[3], abase);
    WAITV(4);                       // bi done; A0 in flight
    st_round(Bs, 0, dA);
    st_round(Bs, 1, dB);
    st_tail(Bs, dT);
    WAIT_LGKM_0();
    barrier_raw();
    GLD_A4(bY[0], bY[1], bY[2], bY[3], abase + TILE);
    // loop invariant at phase head: pending = [A_p(4), A_{p+1}(4)]

// phase p=CJB*5+V: compute CUR (=A_p), prefetch A_{p+2} -> NX2.
// Ledger (STG cjb): v0/v1: w8; v2: dA then A, w16; v3: early w4 + st dA,
//   bi dB/dT then A, w24; v4: early w4 + st dB/dT, A, w8, barrier.
// Last cjb: w8/w8/w8/w4/w0.
#define PHASE(CUR, NX2, CJB, V, STG, DO_PRE, WCMP)                            \
    {                                                                         \
        const unsigned short* BsR = Bs + (((CJB) & 1) ? BSZ : 0);             \
        unsigned short*       BsW = Bs + (((CJB) & 1) ? 0 : BSZ);             \
        if ((STG) && (V) == 3) { WAITV(4); st_round(BsW, 0, dA); }            \
        if ((STG) && (V) == 4) { WAITV(4); st_round(BsW, 1, dB);              \
                                 st_tail(BsW, dT); }                          \
        bf16x8 f0[8], f1[8];                                                  \
        bfread(BsR, (V), 0, lrow, quad, f0);                                  \
        if ((STG) && (V) == 2) bi_round(xb, ((CJB) + 1) * BKCJ, w0, 0, dA);   \
        if ((STG) && (V) == 3) { bi_round(xb, ((CJB) + 1) * BKCJ, w0, 1, dB); \
                                 bi_tail(xb, ((CJB) + 1) * BKCJ, w0, dT); }   \
        if (DO_PRE) GLD_A4(NX2[0], NX2[1], NX2[2], NX2[3],                    \
                           abase + (size_t)((CJB) * 5 + (V) + 2) * TILE);     \
        WAITV(WCMP);                                                          \
        cl(CUR, 0, f0, acc);                                                  \
        bfread(BsR, (V), 1, lrow, quad, f1);                                  \
        cl(CUR, 1, f1, acc);                                                  \
        if ((STG) && (V) == 4) { WAIT_LGKM_0(); barrier_raw(); }              \
    }

    for (int cp = 0; cp < 2; cp++) {   // cjb triples (0,1,2), (3,4,5)
        const int c0 = cp * 3, c1 = c0 + 1, c2 = c0 + 2;
        PHASE(bX, bZ, c0, 0, 1, 1, 8);
        PHASE(bY, bX, c0, 1, 1, 1, 8);
        PHASE(bZ, bY, c0, 2, 1, 1, 16);
        PHASE(bX, bZ, c0, 3, 1, 1, 24);
        PHASE(bY, bX, c0, 4, 1, 1, 8);
        PHASE(bZ, bY, c1, 0, 1, 1, 8);
        PHASE(bX, bZ, c1, 1, 1, 1, 8);
        PHASE(bY, bX, c1, 2, 1, 1, 16);
        PHASE(bZ, bY, c1, 3, 1, 1, 24);
        PHASE(bX, bZ, c1, 4, 1, 1, 8);
        PHASE(bY, bX, c2, 0, 1, 1, 8);
        PHASE(bZ, bY, c2, 1, 1, 1, 8);
        PHASE(bX, bZ, c2, 2, 1, 1, 16);
        PHASE(bY, bX, c2, 3, 1, 1, 24);
        PHASE(bZ, bY, c2, 4, 1, 1, 8);
    }
    // cjb 6 (stages window 7), cjb 7 (no staging)
    PHASE(bX, bZ, 6, 0, 1, 1, 8);
    PHASE(bY, bX, 6, 1, 1, 1, 8);
    PHASE(bZ, bY, 6, 2, 1, 1, 16);
    PHASE(bX, bZ, 6, 3, 1, 1, 24);
    PHASE(bY, bX, 6, 4, 1, 1, 8);
    PHASE(bZ, bY, 7, 0, 0, 1, 8);
    PHASE(bX, bZ, 7, 1, 0, 1, 8);
    PHASE(bY, bX, 7, 2, 0, 1, 8);
    PHASE(bZ, bY, 7, 3, 0, 0, 4);
    PHASE(bX, bZ, 7, 4, 0, 0, 0);
#undef PHASE

    // ---- epilogue: C/D layout col(n)=lane&15, row(m)=quad*4+e
    #pragma unroll
    for (int mt = 0; mt < 2; mt++) {
        #pragma unroll
        for (int e = 0; e < 4; e++) {
            const int okc = mBase + (wave << 5) + (mt << 4) + (quad << 2) + e;
            const float bv = bias[okc];
            float* orow = out + ((size_t)b * OKch + (size_t)okc) * L_ + w0;
            #pragma unroll
            for (int nt = 0; nt < 8; nt++) {
                const int n = (nt << 4) + lrow;
                orow[n] = acc[mt][nt][e] + bv;
            }
        }
    }
}

extern "C" void kernel_launch(void* const* d_in, const int* in_sizes, int n_in,
                              void* d_out, int out_size, void* d_ws, size_t ws_size,
                              hipStream_t stream) {
    const float* x    = (const float*)d_in[0];  // (8,64,8,4096)
    const float* W    = (const float*)d_in[1];  // (5,64,64,8)
    const float* bias = (const float*)d_in[2];  // (1,64,8,1) -> [512]
    const float* G    = (const float*)d_in[3];  // (8,8,8)
    unsigned short* kernT = (unsigned short*)d_ws;                       // 2.62 MB
    unsigned short* xp    = (unsigned short*)((char*)d_ws + (4 << 20));  // 33.6 MB
    float* out = (float*)d_out;

    prep<<<dim3(640 + 4096), 256, 0, stream>>>(W, G, x, kernT, xp);
    gpconv_mfma<<<dim3(1024), 256, 0, stream>>>(xp, kernT, bias, out);
}

// Round 7
// 180.823 us; speedup vs baseline: 1.0059x; 1.0059x over previous
//
#include <hip/hip_runtime.h>

// GPConv1d: out[b,o,kb,w] = sum_{i,j,c,v} G[i,j,kb] W[v,c,o,i] xpad[b,c,j,w+v] + bias[o,kb]
// GEMM view: out[ok][b,w] = sum_kd kern[ok][kd] X[kd][b,w], M=512, N=32768, K=2560
// R7: wave grid 4x1 -> 2x2. With 4x1 every wave read the FULL B panel from LDS
//     (16 ds_read_b128/phase) -> LDS read pipe 54us/CU > MFMA 41us = binding.
//     2x2: each wave reads its N=64 slice (8 reads/phase) -> LDS ~29us, MFMA
//     becomes the binding pipe. A-frag loads double (8/phase) but wave pairs
//     (0,1) and (2,3) issue identical addresses -> L1 (32KB >> 16KB tile)
//     absorbs the duplication; L2 traffic unchanged. Distance-1 A prefetch
//     (R6 proved distance-2 neutral), 2 reg buffers x 8 frags.
//     Ledger (STG cjb): v0/v1: w8; v2: dA then A', w16; v3: early w8 + st dA,
//     bi dB/dT then A', w24; v4: early w8 + st, A', w8, barrier. cjb7: 8/8/8/8/0.
//     Kept: inline-asm loads + manual vmcnt (never 0 until p=39), bf16-prepadded
//     x, Bs XOR swizzle, 1 lgkm-only barrier/cjb, T5 setprio.

#define C_    64
#define L_    4096
#define PAD_  2
#define OKch  512
#define XSTR  4104      // padded bf16 x row stride (elems); halo [0,1],[4098,4099]

#define BM    128
#define BN    128
#define BKCJ  64
#define NCJB  8
#define NV    5
#define TILE  8192      // kern tile: 128 rows x 64 cols (16 KB), frag-coalesced
#define WIN   132       // Bs rows: w0-2 .. w0+129
#define BSZ   (WIN * 64)  // one Bs buffer: 8448 elems = 16896 B

typedef __bf16 bf16x8 __attribute__((ext_vector_type(8)));
typedef float floatx4 __attribute__((ext_vector_type(4)));

__device__ __forceinline__ unsigned short f2bf(float f) {
    unsigned int u = __float_as_uint(f);
    u += 0x7FFFu + ((u >> 16) & 1u);
    return (unsigned short)(u >> 16);
}

#define WAIT_LGKM_0() asm volatile("s_waitcnt lgkmcnt(0)" ::: "memory")
#define WAITV_(N) asm volatile("s_waitcnt vmcnt(" #N ")" ::: "memory")
#define WAITV(N) do { WAITV_(N); __builtin_amdgcn_sched_barrier(0); } while (0)

__device__ __forceinline__ void barrier_raw() {
    asm volatile("" ::: "memory");
    __builtin_amdgcn_sched_barrier(0);
    __builtin_amdgcn_s_barrier();
    __builtin_amdgcn_sched_barrier(0);
    asm volatile("" ::: "memory");
}

// manual global loads (invisible to compiler's waitcnt inserter)
#define GLD_U32(dst, ptr) \
    asm volatile("global_load_dword %0, %1, off" : "=&v"(dst) : "v"(ptr))
#define GLD_A8(a0, a1, a2, a3, a4, a5, a6, a7, p0, p1)             \
    asm volatile("global_load_dwordx4 %0, %8, off\n\t"             \
                 "global_load_dwordx4 %1, %8, off offset:1024\n\t" \
                 "global_load_dwordx4 %2, %8, off offset:2048\n\t" \
                 "global_load_dwordx4 %3, %8, off offset:3072\n\t" \
                 "global_load_dwordx4 %4, %9, off\n\t"             \
                 "global_load_dwordx4 %5, %9, off offset:1024\n\t" \
                 "global_load_dwordx4 %6, %9, off offset:2048\n\t" \
                 "global_load_dwordx4 %7, %9, off offset:3072"     \
                 : "=&v"(a0), "=&v"(a1), "=&v"(a2), "=&v"(a3),     \
                   "=&v"(a4), "=&v"(a5), "=&v"(a6), "=&v"(a7)      \
                 : "v"(p0), "v"(p1))

// ---- kernel 1: prep = build_kern (blocks 0..639) + x->bf16 pad (blocks 640..4735)
__global__ __launch_bounds__(256) void prep(
    const float* __restrict__ W, const float* __restrict__ G,
    const float* __restrict__ x,
    unsigned short* __restrict__ kernT, unsigned short* __restrict__ xp)
{
    const int bid = blockIdx.x;
    const int tid = threadIdx.x;
    if (bid < 640) {
        __shared__ float Gs[512];
        Gs[tid] = G[tid];
        Gs[tid + 256] = G[tid + 256];
        __syncthreads();

        const int idx  = bid * 256 + tid;    // 0..163839
        const int lrow = idx & 15;
        const int quad = (idx >> 4) & 3;
        const int f    = (idx >> 6) & 15;
        const int mq   = f >> 1;
        const int kk2  = f & 1;
        const int t    = idx >> 10;          // (y*8+cjb)*5+v, 0..159
        const int v    = t % 5;
        const int tc   = t / 5;
        const int cjb  = tc & 7;
        const int y    = tc >> 3;
        const int m    = (mq << 4) | lrow;
        const int ok   = (y << 7) | m;
        const int o    = ok >> 3;
        const int kb   = ok & 7;
        const int c    = (cjb << 3) | (kk2 << 2) | quad;

        const float* Wp = W + (((v * C_ + c) * 64 + o) << 3);
        const float4 w0 = *(const float4*)Wp;
        const float4 w1 = *(const float4*)(Wp + 4);
        const float w[8] = {w0.x, w0.y, w0.z, w0.w, w1.x, w1.y, w1.z, w1.w};

        unsigned int pk[4];
        #pragma unroll
        for (int j = 0; j < 8; j++) {
            float s = 0.f;
            #pragma unroll
            for (int i = 0; i < 8; i++)
                s += Gs[i * 64 + j * 8 + kb] * w[i];
            const unsigned short h = f2bf(s);
            if (j & 1) pk[j >> 1] |= (unsigned int)h << 16;
            else       pk[j >> 1]  = h;
        }
        uint4 uu; uu.x = pk[0]; uu.y = pk[1]; uu.z = pk[2]; uu.w = pk[3];
        *reinterpret_cast<uint4*>(
            &kernT[((size_t)t << 13) + (f << 9) + (quad << 7) + (lrow << 3)]) = uu;
    } else {
        const int row = bid - 640;           // 0..4095 = b*512 + cj
        const float* src = x + (size_t)row * L_;
        unsigned short* dst = xp + (size_t)row * XSTR;
        #pragma unroll
        for (int i = 0; i < 4; i++) {
            const int p = (i * 256 + tid) << 2;
            const float4 fv = *reinterpret_cast<const float4*>(src + p);
            const unsigned int u0 = (unsigned int)f2bf(fv.x) | ((unsigned int)f2bf(fv.y) << 16);
            const unsigned int u1 = (unsigned int)f2bf(fv.z) | ((unsigned int)f2bf(fv.w) << 16);
            *reinterpret_cast<unsigned int*>(dst + 2 + p) = u0;
            *reinterpret_cast<unsigned int*>(dst + 4 + p) = u1;
        }
        if (tid == 0) {
            *reinterpret_cast<unsigned int*>(dst) = 0u;          // w' 0,1
            *reinterpret_cast<unsigned int*>(dst + 4098) = 0u;   // w' 4098,4099
        }
    }
}

// ---- staging helpers: item = (kgrp=idx/66, wpair=idx%66) covers rows nn,nn+1
__device__ __forceinline__ void bi_round(const unsigned short* xp, int cj0,
                                         int w0, int round, unsigned int (&d)[8]) {
    const int idx  = round * 256 + (int)threadIdx.x;
    const int kgrp = idx / 66;
    const int wp   = idx - kgrp * 66;
    const unsigned short* p =
        xp + (size_t)(cj0 + (kgrp << 3)) * XSTR + (size_t)(w0 + (wp << 1));
    GLD_U32(d[0], p);
    GLD_U32(d[1], p + XSTR);
    GLD_U32(d[2], p + 2 * XSTR);
    GLD_U32(d[3], p + 3 * XSTR);
    GLD_U32(d[4], p + 4 * XSTR);
    GLD_U32(d[5], p + 5 * XSTR);
    GLD_U32(d[6], p + 6 * XSTR);
    GLD_U32(d[7], p + 7 * XSTR);
}

__device__ __forceinline__ void bi_tail(const unsigned short* xp, int cj0,
                                        int w0, unsigned int (&d)[8]) {
    const int lane = (int)threadIdx.x & 63;
    const int wave = (int)threadIdx.x >> 6;
    if ((lane & 15) == 0) {
        const int idx  = 512 + (wave << 2) + (lane >> 4);
        const int kgrp = idx / 66;
        const int wp   = idx - kgrp * 66;
        const unsigned short* p =
            xp + (size_t)(cj0 + (kgrp << 3)) * XSTR + (size_t)(w0 + (wp << 1));
        GLD_U32(d[0], p);
        GLD_U32(d[1], p + XSTR);
        GLD_U32(d[2], p + 2 * XSTR);
        GLD_U32(d[3], p + 3 * XSTR);
        GLD_U32(d[4], p + 4 * XSTR);
        GLD_U32(d[5], p + 5 * XSTR);
        GLD_U32(d[6], p + 6 * XSTR);
        GLD_U32(d[7], p + 7 * XSTR);
    }
}

__device__ __forceinline__ void st_item(unsigned short* Bw, int kgrp, int nn,
                                        const unsigned int (&d)[8]) {
    const unsigned int lo0 = (d[0] & 0xffffu) | (d[1] << 16);
    const unsigned int hi0 = (d[0] >> 16)     | (d[1] & 0xffff0000u);
    const unsigned int lo1 = (d[2] & 0xffffu) | (d[3] << 16);
    const unsigned int hi1 = (d[2] >> 16)     | (d[3] & 0xffff0000u);
    const unsigned int lo2 = (d[4] & 0xffffu) | (d[5] << 16);
    const unsigned int hi2 = (d[4] >> 16)     | (d[5] & 0xffff0000u);
    const unsigned int lo3 = (d[6] & 0xffffu) | (d[7] << 16);
    const unsigned int hi3 = (d[6] >> 16)     | (d[7] & 0xffff0000u);
    const int s = kgrp ^ (nn & 7);
    uint4 Lv; Lv.x = lo0; Lv.y = lo1; Lv.z = lo2; Lv.w = lo3;
    uint4 Hv; Hv.x = hi0; Hv.y = hi1; Hv.z = hi2; Hv.w = hi3;
    *reinterpret_cast<uint4*>(&Bw[(nn << 6) + (s << 3)]) = Lv;
    *reinterpret_cast<uint4*>(&Bw[((nn + 1) << 6) + ((s ^ 1) << 3)]) = Hv;
}

__device__ __forceinline__ void st_round(unsigned short* Bw, int round,
                                         const unsigned int (&d)[8]) {
    const int idx  = round * 256 + (int)threadIdx.x;
    const int kgrp = idx / 66;
    const int wp   = idx - kgrp * 66;
    st_item(Bw, kgrp, wp << 1, d);
}

__device__ __forceinline__ void st_tail(unsigned short* Bw,
                                        const unsigned int (&d)[8]) {
    const int lane = (int)threadIdx.x & 63;
    const int wave = (int)threadIdx.x >> 6;
    if ((lane & 15) == 0) {
        const int idx  = 512 + (wave << 2) + (lane >> 4);
        const int kgrp = idx / 66;
        const int wp   = idx - kgrp * 66;
        st_item(Bw, kgrp, wp << 1, d);
    }
}

// ---- B-frag reads: 4 ds_read_b128 for the wave's N=64 slice, one kk2 group
__device__ __forceinline__ void bfread(const unsigned short* BsR, int wn, int v,
                                       int kk2, int lrow, int quad,
                                       bf16x8 (&f)[4]) {
    const int s7  = (lrow + v) & 7;
    const int col = ((((kk2) << 2) | quad) ^ s7) << 3;
    const int rb  = (wn + lrow + v) << 6;
    #pragma unroll
    for (int nt = 0; nt < 4; nt++)
        f[nt] = *reinterpret_cast<const bf16x8*>(&BsR[rb + (nt << 10) + col]);
}

// ---- 16-MFMA cluster for one kk2 group (4 mt x 4 nt)
__device__ __forceinline__ void cl(const bf16x8 (&a)[8], int kk2,
                                   const bf16x8 (&f)[4], floatx4 (&acc)[4][4]) {
    __builtin_amdgcn_s_setprio(1);
    #pragma unroll
    for (int mt = 0; mt < 4; mt++)
        #pragma unroll
        for (int nt = 0; nt < 4; nt++)
            acc[mt][nt] = __builtin_amdgcn_mfma_f32_16x16x32_bf16(
                a[mt * 2 + kk2], f[nt], acc[mt][nt], 0, 0, 0);
    __builtin_amdgcn_s_setprio(0);
}

// ---- kernel 2: MFMA GEMM, 128x128 C-tile, 2x2 wave grid, manual vmcnt pipeline
__global__ __launch_bounds__(256, 2) void gpconv_mfma(
    const unsigned short* __restrict__ xp, const unsigned short* __restrict__ kernT,
    const float* __restrict__ bias, float* __restrict__ out)
{
    __shared__ unsigned short Bs[2 * BSZ];  // 33792 B, double-buffered x window

    const int tid  = threadIdx.x;
    const int lane = tid & 63;
    const int wave = tid >> 6;
    const int lrow = lane & 15;
    const int quad = lane >> 4;
    const int wm   = (wave >> 1) << 6;   // 2x2 grid: wave's 64 m-rows
    const int wn   = (wave & 1) << 6;    //           wave's 64 n-cols

    // XCD-aware remap: 4 y-blocks sharing an x-window land on the same XCD
    const int bid = blockIdx.x;              // 0..1023
    const int y   = (bid >> 3) & 3;
    const int xw  = ((bid >> 5) << 3) + (bid & 7);  // 0..255
    const int b   = xw >> 5;
    const int w0  = (xw & 31) * BN;
    const int mBase = y * BM;
    const unsigned short* xb = xp + (size_t)b * (size_t)(512 * XSTR);
    const unsigned short* ky = kernT + (size_t)(y * NCJB) * NV * TILE;
    // wave's A slot: m-half (wave>>1) = frags f0..7 offset (wave>>1)*4096 elems
    const unsigned short* abase = ky + ((wave >> 1) << 12) + (lane << 3);

    floatx4 acc[4][4];
    {
        const floatx4 z = {0.f, 0.f, 0.f, 0.f};
        #pragma unroll
        for (int i2 = 0; i2 < 4; i2++)
            #pragma unroll
            for (int j2 = 0; j2 < 4; j2++) acc[i2][j2] = z;
    }

    bf16x8 aX[8], aY[8];
    unsigned int dA[8], dB[8], dT[8];

    // ---- prologue: window(cjb=0); A0 -> aX.
    bi_round(xb, 0, w0, 0, dA);
    bi_round(xb, 0, w0, 1, dB);
    bi_tail(xb, 0, w0, dT);
    GLD_A8(aX[0], aX[1], aX[2], aX[3], aX[4], aX[5], aX[6], aX[7],
           abase, abase + 2048);
    WAITV(8);                       // bi(24) done; A0(8) in flight
    st_round(Bs, 0, dA);
    st_round(Bs, 1, dB);
    st_tail(Bs, dT);
    WAIT_LGKM_0();
    barrier_raw();
    // loop invariant at phase head: pending = [A_p(8)] (+ staging per ledger)

// phase p=CJB*5+V: compute CUR (=A_p), prefetch A_{p+1} -> NXT.
// Ledger (STG cjb): v0/v1: w8; v2: dA8 then A', w16; v3: early w8 + st dA,
//   dB8+dT8 then A', w24; v4: early w8 + st dB/dT, A', w8, barrier.
// cjb7: w8/w8/w8/w8/w0.
#define PHASE(CUR, NXT, CJB, V, STG, DO_PRE, WCMP)                            \
    {                                                                         \
        const unsigned short* BsR = Bs + (((CJB) & 1) ? BSZ : 0);             \
        unsigned short*       BsW = Bs + (((CJB) & 1) ? 0 : BSZ);             \
        if ((STG) && (V) == 3) { WAITV(8); st_round(BsW, 0, dA); }            \
        if ((STG) && (V) == 4) { WAITV(8); st_round(BsW, 1, dB);              \
                                 st_tail(BsW, dT); }                          \
        bf16x8 f0[4], f1[4];                                                  \
        bfread(BsR, wn, (V), 0, lrow, quad, f0);                              \
        if ((STG) && (V) == 2) bi_round(xb, ((CJB) + 1) * BKCJ, w0, 0, dA);   \
        if ((STG) && (V) == 3) { bi_round(xb, ((CJB) + 1) * BKCJ, w0, 1, dB); \
                                 bi_tail(xb, ((CJB) + 1) * BKCJ, w0, dT); }   \
        if (DO_PRE) {                                                         \
            const unsigned short* ap =                                        \
                abase + (size_t)((CJB) * 5 + (V) + 1) * TILE;                 \
            GLD_A8(NXT[0], NXT[1], NXT[2], NXT[3],                            \
                   NXT[4], NXT[5], NXT[6], NXT[7], ap, ap + 2048);            \
        }                                                                     \
        WAITV(WCMP);                                                          \
        cl(CUR, 0, f0, acc);                                                  \
        bfread(BsR, wn, (V), 1, lrow, quad, f1);                              \
        cl(CUR, 1, f1, acc);                                                  \
        if ((STG) && (V) == 4) { WAIT_LGKM_0(); barrier_raw(); }              \
    }

    for (int cp = 0; cp < 3; cp++) {   // cjb pairs (0,1),(2,3),(4,5)
        const int c0 = cp * 2, c1 = c0 + 1;
        PHASE(aX, aY, c0, 0, 1, 1, 8);
        PHASE(aY, aX, c0, 1, 1, 1, 8);
        PHASE(aX, aY, c0, 2, 1, 1, 16);
        PHASE(aY, aX, c0, 3, 1, 1, 24);
        PHASE(aX, aY, c0, 4, 1, 1, 8);
        PHASE(aY, aX, c1, 0, 1, 1, 8);
        PHASE(aX, aY, c1, 1, 1, 1, 8);
        PHASE(aY, aX, c1, 2, 1, 1, 16);
        PHASE(aX, aY, c1, 3, 1, 1, 24);
        PHASE(aY, aX, c1, 4, 1, 1, 8);
    }
    // cjb 6 (stages window 7), cjb 7 (no staging)
    PHASE(aX, aY, 6, 0, 1, 1, 8);
    PHASE(aY, aX, 6, 1, 1, 1, 8);
    PHASE(aX, aY, 6, 2, 1, 1, 16);
    PHASE(aY, aX, 6, 3, 1, 1, 24);
    PHASE(aX, aY, 6, 4, 1, 1, 8);
    PHASE(aY, aX, 7, 0, 0, 1, 8);
    PHASE(aX, aY, 7, 1, 0, 1, 8);
    PHASE(aY, aX, 7, 2, 0, 1, 8);
    PHASE(aX, aY, 7, 3, 0, 1, 8);
    PHASE(aY, aX, 7, 4, 0, 0, 0);
#undef PHASE

    // ---- epilogue: C/D layout col(n)=lane&15, row(m)=quad*4+e
    #pragma unroll
    for (int mt = 0; mt < 4; mt++) {
        #pragma unroll
        for (int e = 0; e < 4; e++) {
            const int okc = mBase + wm + (mt << 4) + (quad << 2) + e;
            const float bv = bias[okc];
            float* orow = out + ((size_t)b * OKch + (size_t)okc) * L_ + w0;
            #pragma unroll
            for (int nt = 0; nt < 4; nt++) {
                const int n = wn + (nt << 4) + lrow;
                orow[n] = acc[mt][nt][e] + bv;
            }
        }
    }
}

extern "C" void kernel_launch(void* const* d_in, const int* in_sizes, int n_in,
                              void* d_out, int out_size, void* d_ws, size_t ws_size,
                              hipStream_t stream) {
    const float* x    = (const float*)d_in[0];  // (8,64,8,4096)
    const float* W    = (const float*)d_in[1];  // (5,64,64,8)
    const float* bias = (const float*)d_in[2];  // (1,64,8,1) -> [512]
    const float* G    = (const float*)d_in[3];  // (8,8,8)
    unsigned short* kernT = (unsigned short*)d_ws;                       // 2.62 MB
    unsigned short* xp    = (unsigned short*)((char*)d_ws + (4 << 20));  // 33.6 MB
    float* out = (float*)d_out;

    prep<<<dim3(640 + 4096), 256, 0, stream>>>(W, G, x, kernT, xp);
    gpconv_mfma<<<dim3(1024), 256, 0, stream>>>(xp, kernT, bias, out);
}